// Round 7
// baseline (244.933 us; speedup 1.0000x reference)
//
#include <hip/hip_runtime.h>

// InternalInteraction: out[b,j,d] = sum_i [ relu((x_i*x_j)@W1^T + b1) @ W2^T + b2 ]
// Factored: hsum[b,j,h] = sum_i relu((x_i*x_j)@W1^T + b1); out = hsum@W2^T + 16*b2.
// B=2048, A=16, D=128, H=512. Storage fp32 (bf16-rounded values); MFMA in bf16.
//
// Round-7: "registers the allocator will actually keep".
//  r3/r5/r6 all showed LLVM rematerializes invariant weight loads into the
//  loop once a wave requests >~64 resident VGPRs (r6: requested 64-reg w1f,
//  got VGPR_Count=88 and an L2-stream-bound loop at 3.5k cyc/iter).
//  Fix: 1024-thread blocks (16 waves), each wave owns only 32 h ->
//  w1f = 32 VGPRs. Total live ~95 regs, within the 128-reg budget that
//  launch_bounds(1024) itself implies -> nothing to remat, 4 waves/SIMD.
//  Full 16x16x128 pair tensor built once in LDS (70 KB, one barrier);
//  the 16-iteration MFMA loop is completely barrier-free.

#define BATCH 2048
#define AA 16
#define DD 128
#define HH 512

typedef __bf16 bf16;
typedef bf16  bf16x2 __attribute__((ext_vector_type(2)));
typedef bf16  bf16x8 __attribute__((ext_vector_type(8)));
typedef float f32x2  __attribute__((ext_vector_type(2)));
typedef float f32x4  __attribute__((ext_vector_type(4)));

__device__ inline f32x4 splat4(float v) { f32x4 r = {v, v, v, v}; return r; }

__device__ inline bf16x8 cvt8(const f32x4& lo, const f32x4& hi) {
    bf16x8 r;
    r[0] = (bf16)lo[0]; r[1] = (bf16)lo[1]; r[2] = (bf16)lo[2]; r[3] = (bf16)lo[3];
    r[4] = (bf16)hi[0]; r[5] = (bf16)hi[1]; r[6] = (bf16)hi[2]; r[7] = (bf16)hi[3];
    return r;
}

// One block per batch b. 1024 threads = 16 waves; wave w owns H cols
// [w*32, w*32+32) for GEMM1. Waves 0..7 own D cols [w*16, w*16+16) for GEMM2.
__global__ __launch_bounds__(1024)
void interact_kernel(const float* __restrict__ x,   // [B, A, D] fp32
                     const float* __restrict__ W1,  // [H, D]
                     const float* __restrict__ b1,  // [H]
                     const float* __restrict__ W2,  // [D, H]
                     const float* __restrict__ b2,  // [D]
                     float* __restrict__ out)       // [B, A, D] fp32
{
    // Row strides 136/520 bf16 = 272B/1040B = 16B*odd: all b128 reads stay
    // 16B-aligned and the pow-2 bank stride is broken (2-way alias = free).
    __shared__ bf16 xs[16][136];          // x_b                      (4.3 KB)
    __shared__ bf16 ps[16][16][136];      // full pair tensor         (69.6 KB)
    __shared__ bf16 hs[16][520];          // hsum re-layout for GEMM2 (16.6 KB)

    const int b    = blockIdx.x;
    const int tid  = threadIdx.x;
    const int wave = tid >> 6;
    const int lane = tid & 63;
    const int quad = lane >> 4;   // 0..3
    const int col  = lane & 15;   // 0..15

    // build-phase coords: thread owns (jrow, dq..dq+2)
    const int jrow = tid >> 6;          // 0..15  (same as wave)
    const int dq   = (tid & 63) * 2;    // 0..126

    // ---- stage x_b into LDS as bf16 (2 elems/thread) ----
    bf16x2 xjb;
    {
        f32x2 v = *(const f32x2*)(x + (size_t)b * (AA * DD) + jrow * DD + dq);
        xjb[0] = (bf16)v[0]; xjb[1] = (bf16)v[1];
        *(bf16x2*)(&xs[jrow][dq]) = xjb;
    }

    // ---- W1 fragments: ONLY 32 VGPRs/wave -> allocator keeps them ----
    // B-operand layout: lane holds B[k = kk*32 + quad*8 + e][n = col],
    // from row-major [N,K]; W1 is [H,D] = [n][k].
    bf16x8 w1f[2][4];
    float  b1f[2];
#pragma unroll
    for (int n = 0; n < 2; ++n) {
        int h  = wave * 32 + n * 16 + col;
        b1f[n] = b1[h];
#pragma unroll
        for (int kk = 0; kk < 4; ++kk) {
            const float* s = W1 + h * DD + kk * 32 + quad * 8;
            w1f[n][kk] = cvt8(*(const f32x4*)s, *(const f32x4*)(s + 4));
        }
    }

    f32x4 hsum[2];
    hsum[0] = splat4(0.f); hsum[1] = splat4(0.f);

    __syncthreads();   // xs ready

    // ---- build ALL pair tiles: ps[i][j][d] = bf16(x_i[d]*x_j[d]) ----
    {
        float xj0 = (float)xjb[0], xj1 = (float)xjb[1];
#pragma unroll
        for (int i = 0; i < 16; ++i) {
            bf16x2 xi = *(bf16x2*)(&xs[i][dq]);
            bf16x2 pr;
            pr[0] = (bf16)(xj0 * (float)xi[0]);
            pr[1] = (bf16)(xj1 * (float)xi[1]);
            *(bf16x2*)(&ps[i][jrow][dq]) = pr;
        }
    }
    __syncthreads();   // ps ready; i-loop below is barrier-free

    // ---- i-loop: 4 ds_read_b128 + 8 MFMA + 8 fmax/add per i, NO barriers ----
#pragma unroll 2
    for (int i = 0; i < 16; ++i) {
        bf16x8 af[4];
#pragma unroll
        for (int kk = 0; kk < 4; ++kk)
            af[kk] = *(bf16x8*)(&ps[i][col][kk * 32 + quad * 8]);

        f32x4 acc[2];
        acc[0] = splat4(b1f[0]); acc[1] = splat4(b1f[1]);
#pragma unroll
        for (int kk = 0; kk < 4; ++kk)
#pragma unroll
            for (int n = 0; n < 2; ++n)
                acc[n] = __builtin_amdgcn_mfma_f32_16x16x32_bf16(
                    af[kk], w1f[n][kk], acc[n], 0, 0, 0);

        // relu + accumulate (C/D layout: row j = quad*4+r, col h = lane&15)
#pragma unroll
        for (int n = 0; n < 2; ++n)
#pragma unroll
            for (int r = 0; r < 4; ++r)
                hsum[n][r] += fmaxf(acc[n][r], 0.f);
    }

    // ---- hsum -> LDS (bf16) for GEMM2 A-operand re-layout ----
#pragma unroll
    for (int n = 0; n < 2; ++n)
#pragma unroll
        for (int r = 0; r < 4; ++r)
            hs[quad * 4 + r][wave * 32 + n * 16 + col] = (bf16)hsum[n][r];

    __syncthreads();

    // ---- GEMM2 (waves 0..7): out[j,d] = hsum[j,:] @ W2^T + 16*b2 ----
    // M=16 (j), N=16 per wave (d), K=512 (h); W2 streamed from L2.
    if (wave < 8) {
        const int d2 = wave * 16 + col;
        f32x4 acc2 = splat4(16.f * b2[d2]);
#pragma unroll
        for (int ks = 0; ks < 16; ++ks) {
            bf16x8 a2 = *(bf16x8*)(&hs[col][ks * 32 + quad * 8]);
            const float* s = W2 + d2 * HH + ks * 32 + quad * 8;
            bf16x8 bw = cvt8(*(const f32x4*)s, *(const f32x4*)(s + 4));
            acc2 = __builtin_amdgcn_mfma_f32_16x16x32_bf16(a2, bw, acc2, 0, 0, 0);
        }
#pragma unroll
        for (int r = 0; r < 4; ++r)
            out[(size_t)b * (AA * DD) + (quad * 4 + r) * DD + d2] = acc2[r];
    }
}

extern "C" void kernel_launch(void* const* d_in, const int* in_sizes, int n_in,
                              void* d_out, int out_size, void* d_ws, size_t ws_size,
                              hipStream_t stream)
{
    const float* x  = (const float*)d_in[0];  // [2048,16,128]
    const float* W1 = (const float*)d_in[1];  // [512,128]
    const float* b1 = (const float*)d_in[2];  // [512]
    const float* W2 = (const float*)d_in[3];  // [128,512]
    const float* b2 = (const float*)d_in[4];  // [128]
    float* out = (float*)d_out;

    interact_kernel<<<BATCH, 1024, 0, stream>>>(x, W1, b1, W2, b2, out);
}

// Round 8
// 224.164 us; speedup vs baseline: 1.0926x; 1.0926x over previous
//
#include <hip/hip_runtime.h>

// InternalInteraction: out[b,j,d] = sum_i [ relu((x_i*x_j)@W1^T + b1) @ W2^T + b2 ]
// Factored: hsum[b,j,h] = sum_i relu((x_i*x_j)@W1^T + b1); out = hsum@W2^T + 16*b2.
// B=2048, A=16, D=128, H=512. Storage fp32 (bf16-rounded values); MFMA in bf16.
//
// Round-8: ASM-PIN the W1 fragments.
//  r3/r5/r6/r7 (requests of 128/128/64/32 resident regs) ALL collapsed to the
//  same ~3.5k cyc/iter: LLVM rematerializes invariant global loads into the
//  loop instead of holding registers, at any request size. Fix: pass each
//  fragment through `asm volatile("" : "+v")` -- the value becomes opaque
//  (non-rematerializable), so it must stay register-resident.
//  Geometry = r3 (256 thr, 4 waves, wave owns 128 h, A-frag reuse 8 -> LDS
//  A-traffic 385 cyc/CU/iter vs MFMA 1.24k: MFMA-bound once W1 is resident).
//  Barrier-free i-loop over a full 16x16x128 pair tensor; GEMM2's hs buffer
//  aliases the dead ps region -> 72.25 KB LDS -> 2 blocks/CU.

#define BATCH 2048
#define AA 16
#define DD 128
#define HH 512

typedef __bf16 bf16;
typedef bf16  bf16x8 __attribute__((ext_vector_type(8)));
typedef float f32x4  __attribute__((ext_vector_type(4)));

__device__ inline f32x4 splat4(float v) { f32x4 r = {v, v, v, v}; return r; }

__device__ inline f32x4 cvt8(const f32x4& lo, const f32x4& hi) {
    bf16x8 r;
    r[0] = (bf16)lo[0]; r[1] = (bf16)lo[1]; r[2] = (bf16)lo[2]; r[3] = (bf16)lo[3];
    r[4] = (bf16)hi[0]; r[5] = (bf16)hi[1]; r[6] = (bf16)hi[2]; r[7] = (bf16)hi[3];
    return __builtin_bit_cast(f32x4, r);
}

// One block per batch b. 256 threads = 4 waves; wave w owns H cols
// [w*128, w*128+128) for GEMM1 and D cols [w*32, w*32+32) for GEMM2.
__global__ __launch_bounds__(256)
__attribute__((amdgpu_waves_per_eu(2)))      // min 2 waves/EU -> 256-reg budget
void interact_kernel(const float* __restrict__ x,   // [B, A, D] fp32
                     const float* __restrict__ W1,  // [H, D]
                     const float* __restrict__ b1,  // [H]
                     const float* __restrict__ W2,  // [D, H]
                     const float* __restrict__ b2,  // [D]
                     float* __restrict__ out)       // [B, A, D] fp32
{
    // 72.25 KB total -> 2 blocks/CU. Row strides 136/520 bf16 = 16B*odd:
    // b128 reads stay 16B-aligned, pow-2 bank stride broken.
    __shared__ __align__(16) char smem[16 * 136 * 2 + 16 * 16 * 136 * 2];
    bf16 (*xs)[136]        = reinterpret_cast<bf16(*)[136]>(smem);
    bf16 (*ps)[16][136]    = reinterpret_cast<bf16(*)[16][136]>(smem + 16 * 136 * 2);
    bf16 (*hs)[520]        = reinterpret_cast<bf16(*)[520]>(smem + 16 * 136 * 2); // aliases ps (dead)

    const int b    = blockIdx.x;
    const int tid  = threadIdx.x;
    const int wave = tid >> 6;
    const int lane = tid & 63;
    const int quad = lane >> 4;   // 0..3
    const int col  = lane & 15;   // 0..15

    // build-phase coords: thread owns (jrow, d0..d0+8)
    const int jrow = tid >> 4;          // 0..15
    const int d0   = (tid & 15) * 8;    // 0..120

    // ---- stage x_b into LDS as bf16; keep own chunk for the build ----
    f32x4 xjp;   // pinned-layout container for xj bf16x8
    {
        const float* s = x + (size_t)b * (AA * DD) + jrow * DD + d0;
        xjp = cvt8(*(const f32x4*)s, *(const f32x4*)(s + 4));
        *(f32x4*)(&xs[jrow][d0]) = xjp;
    }

    // ---- W1 fragments: load+convert once, then ASM-PIN (128 VGPRs) ----
    // B-operand layout: lane holds B[k = kk*32 + quad*8 + e][n = col],
    // from row-major [N,K]; W1 is [H,D] = [n][k].
    f32x4 w1f[8][4];
    float b1f[8];
#pragma unroll
    for (int n = 0; n < 8; ++n) {
        int h  = wave * 128 + n * 16 + col;
        b1f[n] = b1[h];
#pragma unroll
        for (int kk = 0; kk < 4; ++kk) {
            const float* s = W1 + h * DD + kk * 32 + quad * 8;
            w1f[n][kk] = cvt8(*(const f32x4*)s, *(const f32x4*)(s + 4));
            asm volatile("" : "+v"(w1f[n][kk]));   // opaque: cannot rematerialize
        }
    }

    f32x4 hsum[8];
#pragma unroll
    for (int n = 0; n < 8; ++n) hsum[n] = splat4(0.f);

    __syncthreads();   // xs ready

    // ---- build the full pair tensor: ps[i][j][d] = bf16(x_i[d]*x_j[d]) ----
    {
        bf16x8 xj = __builtin_bit_cast(bf16x8, xjp);
        float xjf[8];
#pragma unroll
        for (int e = 0; e < 8; ++e) xjf[e] = (float)xj[e];
#pragma unroll
        for (int i = 0; i < 16; ++i) {
            bf16x8 xi = *(bf16x8*)(&xs[i][d0]);
            bf16x8 pr;
#pragma unroll
            for (int e = 0; e < 8; ++e)
                pr[e] = (bf16)(xjf[e] * (float)xi[e]);
            *(bf16x8*)(&ps[i][jrow][d0]) = pr;
        }
    }
    __syncthreads();   // ps ready; the i-loop below has NO barriers

    // ---- i-loop: 4 ds_read_b128 + 32 MFMA + relu-accum per i ----
#pragma unroll 2
    for (int i = 0; i < 16; ++i) {
        bf16x8 af[4];
#pragma unroll
        for (int kk = 0; kk < 4; ++kk)
            af[kk] = *(bf16x8*)(&ps[i][col][kk * 32 + quad * 8]);

        f32x4 acc[8];
#pragma unroll
        for (int n = 0; n < 8; ++n) acc[n] = splat4(b1f[n]);
#pragma unroll
        for (int kk = 0; kk < 4; ++kk)
#pragma unroll
            for (int n = 0; n < 8; ++n)
                acc[n] = __builtin_amdgcn_mfma_f32_16x16x32_bf16(
                    af[kk], __builtin_bit_cast(bf16x8, w1f[n][kk]), acc[n], 0, 0, 0);

        // relu + accumulate (C/D layout: row j = quad*4+r, col h = lane&15)
#pragma unroll
        for (int n = 0; n < 8; ++n)
#pragma unroll
            for (int r = 0; r < 4; ++r)
                hsum[n][r] += fmaxf(acc[n][r], 0.f);
    }

    __syncthreads();   // all ps reads done -> safe to overwrite via hs alias

    // ---- hsum -> LDS (bf16) for GEMM2 A-operand re-layout ----
#pragma unroll
    for (int n = 0; n < 8; ++n)
#pragma unroll
        for (int r = 0; r < 4; ++r)
            hs[quad * 4 + r][wave * 128 + n * 16 + col] = (bf16)hsum[n][r];

    __syncthreads();

    // ---- GEMM2: out[j,d] = hsum[j,:] @ W2^T + 16*b2 ----
    // M=16 (j), N=32 per wave (d), K=512 (h); W2 streamed from L2.
    f32x4 acc2[2];
#pragma unroll
    for (int n2 = 0; n2 < 2; ++n2)
        acc2[n2] = splat4(16.f * b2[wave * 32 + n2 * 16 + col]);

#pragma unroll
    for (int ks = 0; ks < 16; ++ks) {
        int h0 = ks * 32 + quad * 8;
        bf16x8 a2 = *(bf16x8*)(&hs[col][h0]);
#pragma unroll
        for (int n2 = 0; n2 < 2; ++n2) {
            int d = wave * 32 + n2 * 16 + col;
            const float* s = W2 + d * HH + h0;
            bf16x8 bw = __builtin_bit_cast(bf16x8, cvt8(*(const f32x4*)s, *(const f32x4*)(s + 4)));
            acc2[n2] = __builtin_amdgcn_mfma_f32_16x16x32_bf16(a2, bw, acc2[n2], 0, 0, 0);
        }
    }

#pragma unroll
    for (int n2 = 0; n2 < 2; ++n2)
#pragma unroll
        for (int r = 0; r < 4; ++r) {
            int j = quad * 4 + r;
            int d = wave * 32 + n2 * 16 + col;
            out[(size_t)b * (AA * DD) + j * DD + d] = acc2[n2][r];
        }
}

extern "C" void kernel_launch(void* const* d_in, const int* in_sizes, int n_in,
                              void* d_out, int out_size, void* d_ws, size_t ws_size,
                              hipStream_t stream)
{
    const float* x  = (const float*)d_in[0];  // [2048,16,128]
    const float* W1 = (const float*)d_in[1];  // [512,128]
    const float* b1 = (const float*)d_in[2];  // [512]
    const float* W2 = (const float*)d_in[3];  // [128,512]
    const float* b2 = (const float*)d_in[4];  // [128]
    float* out = (float*)d_out;

    interact_kernel<<<BATCH, 256, 0, stream>>>(x, W1, b1, W2, b2, out);
}